// Round 5
// baseline (200.819 us; speedup 1.0000x reference)
//
#include <hip/hip_runtime.h>
#include <hip/hip_bf16.h>

typedef float f32x4 __attribute__((ext_vector_type(4)));
typedef float f32x16 __attribute__((ext_vector_type(16)));
typedef __bf16 bf16x8 __attribute__((ext_vector_type(8)));
typedef __bf16 bf16x4 __attribute__((ext_vector_type(4)));

#define DM 1024
#define SL 2048
#define NHEAD 16
#define LOG2E 1.44269504088896f

static __device__ __forceinline__ f32x4 mfma16(bf16x8 a, bf16x8 b, f32x4 c) {
    return __builtin_amdgcn_mfma_f32_16x16x32_bf16(a, b, c, 0, 0, 0);
}
static __device__ __forceinline__ f32x16 mfma32(bf16x8 a, bf16x8 b, f32x16 c) {
    return __builtin_amdgcn_mfma_f32_32x32x16_bf16(a, b, c, 0, 0, 0);
}

// async global->LDS, 16B/lane; lds dest = wave-uniform base + lane*16
static __device__ __forceinline__ void gload16(const void* g, void* l) {
    __builtin_amdgcn_global_load_lds(
        (const __attribute__((address_space(1))) unsigned*)g,
        (__attribute__((address_space(3))) unsigned*)l, 16, 0, 0);
}

#define BAR __builtin_amdgcn_s_barrier()
#define LGKM0 { asm volatile("s_waitcnt lgkmcnt(0)" ::: "memory"); __builtin_amdgcn_sched_barrier(0); }
#define VMW0 { asm volatile("s_waitcnt vmcnt(0)" ::: "memory"); __builtin_amdgcn_sched_barrier(0); }
#define VMW2 { asm volatile("s_waitcnt vmcnt(2)" ::: "memory"); __builtin_amdgcn_sched_barrier(0); }
#define VMW8 { asm volatile("s_waitcnt vmcnt(8)" ::: "memory"); __builtin_amdgcn_sched_barrier(0); }

static __device__ __forceinline__ unsigned packbf(float lo, float hi) {
    unsigned short lu = __builtin_bit_cast(unsigned short, (__bf16)lo);
    unsigned short hu = __builtin_bit_cast(unsigned short, (__bf16)hi);
    return ((unsigned)hu << 16) | (unsigned)lu;
}

static __device__ __forceinline__ void half_swap(unsigned wa, unsigned wb, int hi,
                                                 unsigned &A, unsigned &B) {
    unsigned pa = (unsigned)__shfl_xor((int)wa, 32);
    unsigned pb = (unsigned)__shfl_xor((int)wb, 32);
    A = hi ? pb : wa;
    B = hi ? wb : pa;
}

// ---------------- cast f32 -> bf16, 8 elems/thread
__global__ __launch_bounds__(256) void cast_kernel(
    const float* __restrict__ x0, const float* __restrict__ x1, const float* __restrict__ x2,
    __bf16* __restrict__ y0, __bf16* __restrict__ y1, __bf16* __restrict__ y2)
{
    const float* x = (blockIdx.y == 0) ? x0 : (blockIdx.y == 1) ? x1 : x2;
    __bf16* y = (blockIdx.y == 0) ? y0 : (blockIdx.y == 1) ? y1 : y2;
    size_t i = ((size_t)blockIdx.x * 256 + threadIdx.x) * 8;
    float4 a = *reinterpret_cast<const float4*>(&x[i]);
    float4 b = *reinterpret_cast<const float4*>(&x[i + 4]);
    bf16x8 o;
    o[0] = (__bf16)a.x; o[1] = (__bf16)a.y; o[2] = (__bf16)a.z; o[3] = (__bf16)a.w;
    o[4] = (__bf16)b.x; o[5] = (__bf16)b.y; o[6] = (__bf16)b.z; o[7] = (__bf16)b.w;
    *reinterpret_cast<bf16x8*>(&y[i]) = o;
}

// ---------------- transpose + cast all 4 weights
__global__ __launch_bounds__(256) void wt4_kernel(
    const float* __restrict__ W0, const float* __restrict__ W1,
    const float* __restrict__ W2, const float* __restrict__ W3,
    __bf16* __restrict__ T0, __bf16* __restrict__ T1,
    __bf16* __restrict__ T2, __bf16* __restrict__ T3)
{
    const float* W = (blockIdx.z == 0) ? W0 : (blockIdx.z == 1) ? W1
                   : (blockIdx.z == 2) ? W2 : W3;
    __bf16* Wt = (blockIdx.z == 0) ? T0 : (blockIdx.z == 1) ? T1
               : (blockIdx.z == 2) ? T2 : T3;
    __shared__ float tle[32][33];
    const int tx = threadIdx.x, ty = threadIdx.y;
    const int n0 = blockIdx.x * 32, k0 = blockIdx.y * 32;
#pragma unroll
    for (int i = 0; i < 4; ++i) {
        int r = ty + 8 * i;
        tle[r][tx] = W[(size_t)(k0 + r) * DM + (n0 + tx)];
    }
    __syncthreads();
#pragma unroll
    for (int i = 0; i < 4; ++i) {
        int r = ty + 8 * i;
        Wt[(size_t)(n0 + r) * DM + (k0 + tx)] = (__bf16)tle[tx][r];
    }
}

// ============ 256x256 8-phase GEMM (T2+T3+T4+T5), K=1024, BK=64 ============
// Y = A(bf16 [M][1024]) @ Wt(bf16 [N][1024])^T + bias
// LDS: 2 buffers x (A 256x64 + B 256x64) bf16 = 128KB. st_16x32 swizzle
// (elem_off bit4 ^= row bit2) applied via pre-swizzled global source on the
// linear global_load_lds dest + swizzled ds_read (rule 21).
__global__ __launch_bounds__(512, 2) void qkv256_kernel(
    const __bf16* __restrict__ xq, const __bf16* __restrict__ xk, const __bf16* __restrict__ xv,
    const __bf16* __restrict__ WtQ, const __bf16* __restrict__ WtK, const __bf16* __restrict__ WtV,
    const float* __restrict__ bq, const float* __restrict__ bk, const float* __restrict__ bv,
    __bf16* __restrict__ Qp, __bf16* __restrict__ Kp, __bf16* __restrict__ Vt)
{
    __shared__ __attribute__((aligned(16))) __bf16 lds[65536];  // 128 KB

    const int z = blockIdx.z;
    const __bf16* A  = (z == 0) ? xq : (z == 1) ? xk : xv;
    const __bf16* Wt = (z == 0) ? WtQ : (z == 1) ? WtK : WtV;
    const float* bias = (z == 0) ? bq : (z == 1) ? bk : bv;
    __bf16* Yb = (z == 0) ? Qp : (z == 1) ? Kp : Vt;
    const int mode = (z == 2) ? 1 : 0;
    const float oscale = (z == 0) ? (0.125f * LOG2E) : 1.0f;  // fold 1/sqrt(Dk)*log2e into Q

    const int r0 = blockIdx.y * 256, c0 = blockIdx.x * 256;
    const int t = threadIdx.x;
    const int w = t >> 6, lane = t & 63;
    const int l15 = lane & 15, lhi = lane >> 4, lhi8 = lhi * 8;
    const int wr = w >> 2, wc = w & 3;

    // staging source coords (inverse-swizzled): chunk c=j*512+t covers phys
    // elems [c*8, c*8+8); logical = phys ^ ((phys>>8 & 1)<<4)
    const int pe0 = t * 8,        le0 = pe0 ^ (((pe0 >> 8) & 1) << 4);
    const int pe1 = 4096 + t * 8, le1 = pe1 ^ (((pe1 >> 8) & 1) << 4);
    const int srow0 = le0 >> 6, scol0 = le0 & 63;
    const int srow1 = le1 >> 6, scol1 = le1 & 63;

    // stage one half-tile (128 rows x 64 k) = 2 gload instructions/thread
    auto stage = [&](int tile, int isB, int h) {
        const int buf = tile & 1, kt = tile * 64;
        const __bf16* src = isB ? Wt : A;
        const int rr = (isB ? c0 : r0) + h * 128;
        const int dbase = buf * 32768 + isB * 16384 + h * 8192 + w * 512;
        gload16(&src[(size_t)(rr + srow0) * DM + kt + scol0], &lds[dbase]);
        gload16(&src[(size_t)(rr + srow1) * DM + kt + scol1], &lds[dbase + 4096]);
    };
    // fragment reads (swizzled)
    auto rdA = [&](int buf, int m, int kk) -> bf16x8 {
        int R = wr * 128 + m * 16 + l15;
        int off = R * 64 + ((kk * 32 + lhi8) ^ (((R >> 2) & 1) << 4));
        return *reinterpret_cast<const bf16x8*>(&lds[buf * 32768 + off]);
    };
    auto rdB = [&](int buf, int n, int kk) -> bf16x8 {
        int R = wc * 64 + n * 16 + l15;
        int off = R * 64 + ((kk * 32 + lhi8) ^ (((R >> 2) & 1) << 4));
        return *reinterpret_cast<const bf16x8*>(&lds[buf * 32768 + 16384 + off]);
    };

    const f32x4 fzero = {0.f, 0.f, 0.f, 0.f};
    f32x4 acc[8][4];
#pragma unroll
    for (int m = 0; m < 8; ++m)
#pragma unroll
        for (int n = 0; n < 4; ++n) acc[m][n] = fzero;

    bf16x8 a[4][2], b[4][2];

#define MFMA8(MB, N0)                                                        \
    _Pragma("unroll") for (int m_ = 0; m_ < 4; ++m_)                          \
    _Pragma("unroll") for (int n_ = 0; n_ < 2; ++n_)                          \
    _Pragma("unroll") for (int k_ = 0; k_ < 2; ++k_)                          \
        acc[(MB) + m_][(N0) + n_] =                                           \
            mfma16(a[m_][k_], b[(N0) + n_][k_], acc[(MB) + m_][(N0) + n_]);

    // prologue: stage tiles 0 (buf0) and 1 (buf1)
    stage(0, 0, 0); stage(0, 0, 1); stage(0, 1, 0); stage(0, 1, 1);
    stage(1, 0, 0); stage(1, 0, 1); stage(1, 1, 0); stage(1, 1, 1);
    VMW8; BAR;

    for (int i = 0; i < 8; ++i) {
        const int tb1 = 2 * i + 1, tnx = 2 * i + 2;
        // ===== K-tile 2i from buf0 =====
        // ph1: read a[m0-3], b[n0-1]; stage tb1.A1
#pragma unroll
        for (int m = 0; m < 4; ++m) { a[m][0] = rdA(0, m, 0); a[m][1] = rdA(0, m, 1); }
#pragma unroll
        for (int n = 0; n < 2; ++n) { b[n][0] = rdB(0, n, 0); b[n][1] = rdB(0, n, 1); }
        if (i > 0) stage(tb1, 0, 1);
        BAR; LGKM0;
        __builtin_amdgcn_s_setprio(1); MFMA8(0, 0); __builtin_amdgcn_s_setprio(0);
        BAR;
        // ph2: read b[n2-3]; stage tb1.B0
#pragma unroll
        for (int n = 2; n < 4; ++n) { b[n][0] = rdB(0, n, 0); b[n][1] = rdB(0, n, 1); }
        if (i > 0) stage(tb1, 1, 0);
        BAR; LGKM0;
        __builtin_amdgcn_s_setprio(1); MFMA8(0, 2); __builtin_amdgcn_s_setprio(0);
        BAR;
        // ph3: read a[m4-7]; stage tb1.B1
#pragma unroll
        for (int m = 0; m < 4; ++m) { a[m][0] = rdA(0, m + 4, 0); a[m][1] = rdA(0, m + 4, 1); }
        if (i > 0) stage(tb1, 1, 1);
        BAR; LGKM0;
        __builtin_amdgcn_s_setprio(1); MFMA8(4, 2); __builtin_amdgcn_s_setprio(0);
        BAR;
        // ph4: stage tnx.A0; MFMA m4-7 x n0-1; counted vmcnt
        if (i < 7) stage(tnx, 0, 0);
        BAR;
        __builtin_amdgcn_s_setprio(1); MFMA8(4, 0); __builtin_amdgcn_s_setprio(0);
        if (i < 7) { VMW2; } else { VMW0; }
        BAR;
        // ===== K-tile 2i+1 from buf1 =====
        // ph5
#pragma unroll
        for (int m = 0; m < 4; ++m) { a[m][0] = rdA(1, m, 0); a[m][1] = rdA(1, m, 1); }
#pragma unroll
        for (int n = 0; n < 2; ++n) { b[n][0] = rdB(1, n, 0); b[n][1] = rdB(1, n, 1); }
        if (i < 7) stage(tnx, 0, 1);
        BAR; LGKM0;
        __builtin_amdgcn_s_setprio(1); MFMA8(0, 0); __builtin_amdgcn_s_setprio(0);
        BAR;
        // ph6
#pragma unroll
        for (int n = 2; n < 4; ++n) { b[n][0] = rdB(1, n, 0); b[n][1] = rdB(1, n, 1); }
        if (i < 7) stage(tnx, 1, 0);
        BAR; LGKM0;
        __builtin_amdgcn_s_setprio(1); MFMA8(0, 2); __builtin_amdgcn_s_setprio(0);
        BAR;
        // ph7
#pragma unroll
        for (int m = 0; m < 4; ++m) { a[m][0] = rdA(1, m + 4, 0); a[m][1] = rdA(1, m + 4, 1); }
        if (i < 7) stage(tnx, 1, 1);
        BAR; LGKM0;
        __builtin_amdgcn_s_setprio(1); MFMA8(4, 2); __builtin_amdgcn_s_setprio(0);
        BAR;
        // ph8: stage (2i+3).A0; MFMA m4-7 x n0-1; counted vmcnt
        if (i < 7) stage(tb1 + 2, 0, 0);
        BAR;
        __builtin_amdgcn_s_setprio(1); MFMA8(4, 0); __builtin_amdgcn_s_setprio(0);
        if (i < 7) { VMW2; BAR; }
    }
#undef MFMA8

    // epilogue
#pragma unroll
    for (int m = 0; m < 8; ++m)
#pragma unroll
        for (int n = 0; n < 4; ++n)
#pragma unroll
            for (int r = 0; r < 4; ++r) {
                int grow = r0 + wr * 128 + m * 16 + lhi * 4 + r;
                int gcol = c0 + wc * 64 + n * 16 + l15;
                float val = acc[m][n][r] + bias[gcol];
                if (mode == 0) {
                    Yb[(size_t)grow * DM + gcol] = (__bf16)(val * oscale);
                } else {
                    int bb = grow >> 11, ss = grow & (SL - 1);
                    int hh = gcol >> 6, dd = gcol & 63;
                    Yb[(((size_t)(bb * NHEAD + hh)) * 64 + dd) * SL + ss] = (__bf16)val;
                }
            }
}

// ---------------- m97-style 128x128 GEMM for the output projection
__global__ __launch_bounds__(256) void oproj_kernel(
    const __bf16* __restrict__ Cxb, const __bf16* __restrict__ WtO,
    const float* __restrict__ bo, const float* __restrict__ resid,
    float* __restrict__ pre)
{
    __shared__ __attribute__((aligned(16))) __bf16 As[128 * 64];
    __shared__ __attribute__((aligned(16))) __bf16 Bs[128 * 64];
    const int r0 = blockIdx.y * 128, c0 = blockIdx.x * 128;
    const int t = threadIdx.x;
    const int w = t >> 6, lane = t & 63;
    const int l15 = lane & 15, lhi = lane >> 4;
    const int wr = w >> 1, wc = w & 1;
    const int lrow = lane >> 3, lcol = (lane & 7) << 3;
    const int jb = w * 4;

    const f32x4 fzero = {0.f, 0.f, 0.f, 0.f};
    f32x4 acc[4][4];
#pragma unroll
    for (int m = 0; m < 4; ++m)
#pragma unroll
        for (int n = 0; n < 4; ++n) acc[m][n] = fzero;

    const __bf16* gA = &Cxb[(size_t)(r0 + jb * 8 + lrow) * DM + lcol];
    const __bf16* gB = &WtO[(size_t)(c0 + jb * 8 + lrow) * DM + lcol];

    for (int kt = 0; kt < DM; kt += 64) {
        __syncthreads();
#pragma unroll
        for (int i = 0; i < 4; ++i) {
            gload16(gA + (size_t)i * 8 * DM + kt, &As[(jb + i) * 512]);
            gload16(gB + (size_t)i * 8 * DM + kt, &Bs[(jb + i) * 512]);
        }
        __syncthreads();
#pragma unroll
        for (int kk = 0; kk < 2; ++kk) {
            bf16x8 af[4], bfr[4];
#pragma unroll
            for (int m = 0; m < 4; ++m)
                af[m] = *reinterpret_cast<const bf16x8*>(
                    &As[(wr * 64 + m * 16 + l15) * 64 + kk * 32 + lhi * 8]);
#pragma unroll
            for (int n = 0; n < 4; ++n)
                bfr[n] = *reinterpret_cast<const bf16x8*>(
                    &Bs[(wc * 64 + n * 16 + l15) * 64 + kk * 32 + lhi * 8]);
#pragma unroll
            for (int m = 0; m < 4; ++m)
#pragma unroll
                for (int n = 0; n < 4; ++n)
                    acc[m][n] = mfma16(af[m], bfr[n], acc[m][n]);
        }
    }
#pragma unroll
    for (int m = 0; m < 4; ++m)
#pragma unroll
        for (int n = 0; n < 4; ++n)
#pragma unroll
            for (int r = 0; r < 4; ++r) {
                int grow = r0 + wr * 64 + m * 16 + lhi * 4 + r;
                int gcol = c0 + wc * 64 + n * 16 + l15;
                size_t idx = (size_t)grow * DM + gcol;
                pre[idx] = acc[m][n][r] + bo[gcol] + resid[idx];
            }
}

// ---------------- flash attention: 8 waves/block, 32 q-rows/wave, 32x32x16
// MFMA, dbuf swizzled LDS K/V + async reg prefetch, in-reg log2-domain softmax.
__global__ __launch_bounds__(512, 2) void attn_kernel(
    const __bf16* __restrict__ Qp, const __bf16* __restrict__ Kp,
    const __bf16* __restrict__ Vt, __bf16* __restrict__ Cxb)
{
    __shared__ __attribute__((aligned(16))) __bf16 Kl[2][4096];
    __shared__ __attribute__((aligned(16))) __bf16 Vl[2][4096];
    const int t = threadIdx.x;
    const int w = t >> 6, lane = t & 63;
    const int l31 = lane & 31, hi = lane >> 5;

    const int id = blockIdx.x;
    const int logical = (id & 7) * 32 + (id >> 3);
    const int bh = logical >> 3, qs = logical & 7;
    const int b = bh >> 4, h = bh & 15;
    const size_t tokQ = (size_t)b * SL + qs * 256 + w * 32;
    const size_t kbase = (size_t)b * SL;
    const size_t vrow0 = (size_t)bh * 64;

    const int srow = t >> 3, scol = (t & 7) << 3;
    const __bf16* gK = &Kp[(kbase + srow) * DM + h * 64 + scol];
    const __bf16* gV = &Vt[(vrow0 + srow) * SL + scol];
    const int sidx = ((srow * 128 + scol * 2) ^ ((srow & 7) << 4)) >> 1;

    bf16x8 bq[4];
#pragma unroll
    for (int ks = 0; ks < 4; ++ks)
        bq[ks] = *reinterpret_cast<const bf16x8*>(
            &Qp[(tokQ + l31) * DM + h * 64 + ks * 16 + hi * 8]);

    f32x16 o0, o1;
#pragma unroll
    for (int r = 0; r < 16; ++r) { o0[r] = 0.f; o1[r] = 0.f; }
    float m_run = -1e30f, l_run = 0.f;   // log2 domain

    const int swz = (l31 & 7) << 4;

    {
        bf16x8 kv = *reinterpret_cast<const bf16x8*>(gK);
        bf16x8 vv = *reinterpret_cast<const bf16x8*>(gV);
        *reinterpret_cast<bf16x8*>(&Kl[0][sidx]) = kv;
        *reinterpret_cast<bf16x8*>(&Vl[0][sidx]) = vv;
    }

    for (int ti = 0; ti < SL / 64; ++ti) {
        const int cb = ti & 1;
        const bool pf = (ti + 1 < SL / 64);
        bf16x8 kvn, vvn;
        if (pf) {
            kvn = *reinterpret_cast<const bf16x8*>(gK + (size_t)(ti + 1) * 64 * DM);
            vvn = *reinterpret_cast<const bf16x8*>(gV + (ti + 1) * 64);
        }
        __syncthreads();

        f32x16 c0, c1;
#pragma unroll
        for (int r = 0; r < 16; ++r) { c0[r] = 0.f; c1[r] = 0.f; }
        __builtin_amdgcn_s_setprio(1);
#pragma unroll
        for (int ks = 0; ks < 4; ++ks) {
            int off = ks * 32 + hi * 16;
            bf16x8 ak0 = *reinterpret_cast<const bf16x8*>(&Kl[cb][((l31 * 128 + off) ^ swz) >> 1]);
            bf16x8 ak1 = *reinterpret_cast<const bf16x8*>(&Kl[cb][(((32 + l31) * 128 + off) ^ swz) >> 1]);
            c0 = mfma32(ak0, bq[ks], c0);
            c1 = mfma32(ak1, bq[ks], c1);
        }
        __builtin_amdgcn_s_setprio(0);

        float tm = c0[0];
#pragma unroll
        for (int r = 1; r < 16; ++r) tm = fmaxf(tm, c0[r]);
#pragma unroll
        for (int r = 0; r < 16; ++r) tm = fmaxf(tm, c1[r]);
        tm = fmaxf(tm, __shfl_xor(tm, 32));

        if (__any(tm > m_run + 11.5f)) {   // defer-max (e^8 in log2 units)
            float nm = fmaxf(m_run, tm);
            float sc = exp2f(m_run - nm);
            m_run = nm;
            l_run *= sc;
#pragma unroll
            for (int r = 0; r < 16; ++r) {
                float sq = __shfl(sc, (r & 3) + 8 * (r >> 2) + 4 * hi);
                o0[r] *= sq; o1[r] *= sq;
            }
        }

        float rs = 0.f;
#pragma unroll
        for (int r = 0; r < 16; ++r) { c0[r] = exp2f(c0[r] - m_run); rs += c0[r]; }
#pragma unroll
        for (int r = 0; r < 16; ++r) { c1[r] = exp2f(c1[r] - m_run); rs += c1[r]; }
        rs += __shfl_xor(rs, 32);
        l_run += rs;

        unsigned wd0[8], wd1[8];
#pragma unroll
        for (int tt = 0; tt < 4; ++tt)
#pragma unroll
            for (int p = 0; p < 2; ++p) {
                wd0[tt * 2 + p] = packbf(c0[4 * tt + 2 * p], c0[4 * tt + 2 * p + 1]);
                wd1[tt * 2 + p] = packbf(c1[4 * tt + 2 * p], c1[4 * tt + 2 * p + 1]);
            }
        unsigned ua[4][4];
#pragma unroll
        for (int s = 0; s < 4; ++s) {
            int tA = (s & 1) * 2;
#pragma unroll
            for (int p = 0; p < 2; ++p) {
                unsigned A, B;
                if (s < 2) half_swap(wd0[tA * 2 + p], wd0[(tA + 1) * 2 + p], hi, A, B);
                else       half_swap(wd1[tA * 2 + p], wd1[(tA + 1) * 2 + p], hi, A, B);
                ua[s][p] = A; ua[s][2 + p] = B;
            }
        }

        __builtin_amdgcn_s_setprio(1);
#pragma unroll
        for (int s = 0; s < 4; ++s) {
            bf16x8 as = *reinterpret_cast<const bf16x8*>(&ua[s][0]);
            bf16x8 vf0 = *reinterpret_cast<const bf16x8*>(
                &Vl[cb][((l31 * 128 + s * 32 + hi * 16) ^ swz) >> 1]);
            bf16x8 vf1 = *reinterpret_cast<const bf16x8*>(
                &Vl[cb][(((32 + l31) * 128 + s * 32 + hi * 16) ^ swz) >> 1]);
            o0 = mfma32(as, vf0, o0);
            o1 = mfma32(as, vf1, o1);
        }
        __builtin_amdgcn_s_setprio(0);

        if (pf) {
            *reinterpret_cast<bf16x8*>(&Kl[cb ^ 1][sidx]) = kvn;
            *reinterpret_cast<bf16x8*>(&Vl[cb ^ 1][sidx]) = vvn;
        }
    }

#pragma unroll
    for (int r = 0; r < 16; ++r) {
        int qq = (r & 3) + 8 * (r >> 2) + 4 * hi;
        float inv = 1.f / __shfl(l_run, qq);
        size_t rowi = (tokQ + qq) * DM + h * 64;
        Cxb[rowi + l31]      = (__bf16)(o0[r] * inv);
        Cxb[rowi + 32 + l31] = (__bf16)(o1[r] * inv);
    }
}

// ---------------- LayerNorm over rows of 1024
__global__ __launch_bounds__(256) void ln_kernel(
    const float* __restrict__ X, const float* __restrict__ gamma,
    const float* __restrict__ beta, float* __restrict__ out)
{
    const int row = blockIdx.x, t = threadIdx.x;
    float4 v = *reinterpret_cast<const float4*>(&X[(size_t)row * DM + t * 4]);
    float s = v.x + v.y + v.z + v.w;
    float s2 = v.x * v.x + v.y * v.y + v.z * v.z + v.w * v.w;
#pragma unroll
    for (int off = 1; off < 64; off <<= 1) {
        s += __shfl_xor(s, off);
        s2 += __shfl_xor(s2, off);
    }
    __shared__ float rs[4], rs2[4];
    const int w = t >> 6;
    if ((t & 63) == 0) { rs[w] = s; rs2[w] = s2; }
    __syncthreads();
    s = rs[0] + rs[1] + rs[2] + rs[3];
    s2 = rs2[0] + rs2[1] + rs2[2] + rs2[3];
    float mean = s * (1.f / DM);
    float var = s2 * (1.f / DM) - mean * mean;
    float rstd = rsqrtf(var + 1e-5f);
    int c = t * 4;
    float4 o;
    o.x = (v.x - mean) * rstd * gamma[c + 0] + beta[c + 0];
    o.y = (v.y - mean) * rstd * gamma[c + 1] + beta[c + 1];
    o.z = (v.z - mean) * rstd * gamma[c + 2] + beta[c + 2];
    o.w = (v.w - mean) * rstd * gamma[c + 3] + beta[c + 3];
    *reinterpret_cast<float4*>(&out[(size_t)row * DM + c]) = o;
}

extern "C" void kernel_launch(void* const* d_in, const int* in_sizes, int n_in,
                              void* d_out, int out_size, void* d_ws, size_t ws_size,
                              hipStream_t stream) {
    (void)in_sizes; (void)n_in; (void)out_size; (void)ws_size;
    const float* q   = (const float*)d_in[0];
    const float* k   = (const float*)d_in[1];
    const float* v   = (const float*)d_in[2];
    const float* Wq  = (const float*)d_in[3];
    const float* bq  = (const float*)d_in[4];
    const float* Wk  = (const float*)d_in[5];
    const float* bk  = (const float*)d_in[6];
    const float* Wv  = (const float*)d_in[7];
    const float* bv  = (const float*)d_in[8];
    const float* Wo  = (const float*)d_in[9];
    const float* bo  = (const float*)d_in[10];
    const float* lng = (const float*)d_in[11];
    const float* lnb = (const float*)d_in[12];

    char* ws = (char*)d_ws;
    const size_t MB = (size_t)1 << 20;
    __bf16* WtQ = (__bf16*)(ws + 0 * MB);
    __bf16* WtK = (__bf16*)(ws + 2 * MB);
    __bf16* WtV = (__bf16*)(ws + 4 * MB);
    __bf16* WtO = (__bf16*)(ws + 6 * MB);
    __bf16* Xbq = (__bf16*)(ws + 8 * MB);    // [4096][1024] bf16
    __bf16* Xbk = (__bf16*)(ws + 16 * MB);
    __bf16* Xbv = (__bf16*)(ws + 24 * MB);
    __bf16* Qp  = (__bf16*)(ws + 32 * MB);   // pre-scaled by log2e/8
    __bf16* Kp  = (__bf16*)(ws + 40 * MB);
    __bf16* Vt  = (__bf16*)(ws + 48 * MB);   // [b][h][64][2048]
    __bf16* Cxb = (__bf16*)(ws + 56 * MB);   // ctx bf16 [4096][1024]
    float*  pre = (float*)(ws + 8 * MB);     // reuse Xbq/Xbk (dead after qkv)

    cast_kernel<<<dim3(2048, 3), 256, 0, stream>>>(q, k, v, Xbq, Xbk, Xbv);
    wt4_kernel<<<dim3(32, 32, 4), dim3(32, 8), 0, stream>>>(
        Wq, Wk, Wv, Wo, WtQ, WtK, WtV, WtO);

    qkv256_kernel<<<dim3(4, 16, 3), 512, 0, stream>>>(Xbq, Xbk, Xbv, WtQ, WtK, WtV,
                                                      bq, bk, bv, Qp, Kp, Vt);
    attn_kernel<<<dim3(256), 512, 0, stream>>>(Qp, Kp, Vt, Cxb);
    oproj_kernel<<<dim3(8, 32), 256, 0, stream>>>(Cxb, WtO, bo, q, pre);
    ln_kernel<<<4096, 256, 0, stream>>>(pre, lng, lnb, (float*)d_out);
}

// Round 6
// 176.384 us; speedup vs baseline: 1.1385x; 1.1385x over previous
//
#include <hip/hip_runtime.h>
#include <hip/hip_bf16.h>

typedef float f32x4 __attribute__((ext_vector_type(4)));
typedef float f32x16 __attribute__((ext_vector_type(16)));
typedef __bf16 bf16x8 __attribute__((ext_vector_type(8)));
typedef __bf16 bf16x4 __attribute__((ext_vector_type(4)));

#define DM 1024
#define SL 2048
#define NHEAD 16

static __device__ __forceinline__ f32x4 mfma16(bf16x8 a, bf16x8 b, f32x4 c) {
    return __builtin_amdgcn_mfma_f32_16x16x32_bf16(a, b, c, 0, 0, 0);
}
static __device__ __forceinline__ f32x16 mfma32(bf16x8 a, bf16x8 b, f32x16 c) {
    return __builtin_amdgcn_mfma_f32_32x32x16_bf16(a, b, c, 0, 0, 0);
}

// async global->LDS, 16B/lane; lds dest = wave-uniform base + lane*16
static __device__ __forceinline__ void gload16(const void* g, void* l) {
    __builtin_amdgcn_global_load_lds(
        (const __attribute__((address_space(1))) unsigned*)g,
        (__attribute__((address_space(3))) unsigned*)l, 16, 0, 0);
}

static __device__ __forceinline__ unsigned packbf(float lo, float hi) {
    unsigned short lu = __builtin_bit_cast(unsigned short, (__bf16)lo);
    unsigned short hu = __builtin_bit_cast(unsigned short, (__bf16)hi);
    return ((unsigned)hu << 16) | (unsigned)lu;
}

static __device__ __forceinline__ void half_swap(unsigned wa, unsigned wb, int hi,
                                                 unsigned &A, unsigned &B) {
    unsigned pa = (unsigned)__shfl_xor((int)wa, 32);
    unsigned pb = (unsigned)__shfl_xor((int)wb, 32);
    A = hi ? pb : wa;
    B = hi ? wb : pa;
}

// ---------------- cast f32 -> bf16, 8 elems/thread
__global__ __launch_bounds__(256) void cast_kernel(
    const float* __restrict__ x0, const float* __restrict__ x1, const float* __restrict__ x2,
    __bf16* __restrict__ y0, __bf16* __restrict__ y1, __bf16* __restrict__ y2)
{
    const float* x = (blockIdx.y == 0) ? x0 : (blockIdx.y == 1) ? x1 : x2;
    __bf16* y = (blockIdx.y == 0) ? y0 : (blockIdx.y == 1) ? y1 : y2;
    size_t i = ((size_t)blockIdx.x * 256 + threadIdx.x) * 8;
    float4 a = *reinterpret_cast<const float4*>(&x[i]);
    float4 b = *reinterpret_cast<const float4*>(&x[i + 4]);
    bf16x8 o;
    o[0] = (__bf16)a.x; o[1] = (__bf16)a.y; o[2] = (__bf16)a.z; o[3] = (__bf16)a.w;
    o[4] = (__bf16)b.x; o[5] = (__bf16)b.y; o[6] = (__bf16)b.z; o[7] = (__bf16)b.w;
    *reinterpret_cast<bf16x8*>(&y[i]) = o;
}

// ---------------- transpose + cast all 4 weights
__global__ __launch_bounds__(256) void wt4_kernel(
    const float* __restrict__ W0, const float* __restrict__ W1,
    const float* __restrict__ W2, const float* __restrict__ W3,
    __bf16* __restrict__ T0, __bf16* __restrict__ T1,
    __bf16* __restrict__ T2, __bf16* __restrict__ T3)
{
    const float* W = (blockIdx.z == 0) ? W0 : (blockIdx.z == 1) ? W1
                   : (blockIdx.z == 2) ? W2 : W3;
    __bf16* Wt = (blockIdx.z == 0) ? T0 : (blockIdx.z == 1) ? T1
               : (blockIdx.z == 2) ? T2 : T3;
    __shared__ float tle[32][33];
    const int tx = threadIdx.x, ty = threadIdx.y;
    const int n0 = blockIdx.x * 32, k0 = blockIdx.y * 32;
#pragma unroll
    for (int i = 0; i < 4; ++i) {
        int r = ty + 8 * i;
        tle[r][tx] = W[(size_t)(k0 + r) * DM + (n0 + tx)];
    }
    __syncthreads();
#pragma unroll
    for (int i = 0; i < 4; ++i) {
        int r = ty + 8 * i;
        Wt[(size_t)(n0 + r) * DM + (k0 + tx)] = (__bf16)tle[tx][r];
    }
}

// ---------------- m97-style GEMM: A bf16 [M][1024] @ Wt bf16 [N][1024]^T
// 128x128 tile, BK=64, global_load_lds staging, 4 waves (2x2), 16x16x32 MFMA.
static __device__ __forceinline__ void gemm_body_bf16(
    const __bf16* __restrict__ A, const __bf16* __restrict__ Wt,
    const float* __restrict__ bias, const float* __restrict__ resid,
    __bf16* __restrict__ Yb, float* __restrict__ Yf,
    int mode, float oscale, int r0, int c0)
{
    __shared__ __attribute__((aligned(16))) __bf16 As[128 * 64];
    __shared__ __attribute__((aligned(16))) __bf16 Bs[128 * 64];
    const int t = threadIdx.x;
    const int w = t >> 6, lane = t & 63;
    const int l15 = lane & 15, lhi = lane >> 4;
    const int wr = w >> 1, wc = w & 1;
    const int lrow = lane >> 3, lcol = (lane & 7) << 3;
    const int jb = w * 4;

    const f32x4 fzero = {0.f, 0.f, 0.f, 0.f};
    f32x4 acc[4][4];
#pragma unroll
    for (int m = 0; m < 4; ++m)
#pragma unroll
        for (int n = 0; n < 4; ++n) acc[m][n] = fzero;

    const __bf16* gA = &A[(size_t)(r0 + jb * 8 + lrow) * DM + lcol];
    const __bf16* gB = &Wt[(size_t)(c0 + jb * 8 + lrow) * DM + lcol];

    for (int kt = 0; kt < DM; kt += 64) {
        __syncthreads();
#pragma unroll
        for (int i = 0; i < 4; ++i) {
            gload16(gA + (size_t)i * 8 * DM + kt, &As[(jb + i) * 512]);
            gload16(gB + (size_t)i * 8 * DM + kt, &Bs[(jb + i) * 512]);
        }
        __syncthreads();
#pragma unroll
        for (int kk = 0; kk < 2; ++kk) {
            bf16x8 af[4], bfr[4];
#pragma unroll
            for (int m = 0; m < 4; ++m)
                af[m] = *reinterpret_cast<const bf16x8*>(
                    &As[(wr * 64 + m * 16 + l15) * 64 + kk * 32 + lhi * 8]);
#pragma unroll
            for (int n = 0; n < 4; ++n)
                bfr[n] = *reinterpret_cast<const bf16x8*>(
                    &Bs[(wc * 64 + n * 16 + l15) * 64 + kk * 32 + lhi * 8]);
#pragma unroll
            for (int m = 0; m < 4; ++m)
#pragma unroll
                for (int n = 0; n < 4; ++n)
                    acc[m][n] = mfma16(af[m], bfr[n], acc[m][n]);
        }
    }
#pragma unroll
    for (int m = 0; m < 4; ++m)
#pragma unroll
        for (int n = 0; n < 4; ++n)
#pragma unroll
            for (int r = 0; r < 4; ++r) {
                int grow = r0 + wr * 64 + m * 16 + lhi * 4 + r;
                int gcol = c0 + wc * 64 + n * 16 + l15;
                float val = acc[m][n][r] + bias[gcol];
                if (mode == 0) {
                    Yb[(size_t)grow * DM + gcol] = (__bf16)(val * oscale);
                } else if (mode == 1) {
                    int bb = grow >> 11, ss = grow & (SL - 1);
                    int hh = gcol >> 6, dd = gcol & 63;
                    Yb[(((size_t)(bb * NHEAD + hh)) * 64 + dd) * SL + ss] = (__bf16)val;
                } else {
                    size_t idx = (size_t)grow * DM + gcol;
                    Yf[idx] = val + resid[idx];
                }
            }
}

__global__ __launch_bounds__(256) void qkv_kernel(
    const __bf16* __restrict__ xq, const __bf16* __restrict__ xk, const __bf16* __restrict__ xv,
    const __bf16* __restrict__ WtQ, const __bf16* __restrict__ WtK, const __bf16* __restrict__ WtV,
    const float* __restrict__ bq, const float* __restrict__ bk, const float* __restrict__ bv,
    __bf16* __restrict__ Qp, __bf16* __restrict__ Kp, __bf16* __restrict__ Vt)
{
    const int z = blockIdx.z;
    const __bf16* X = (z == 0) ? xq : (z == 1) ? xk : xv;
    const __bf16* Wt = (z == 0) ? WtQ : (z == 1) ? WtK : WtV;
    const float* bias = (z == 0) ? bq : (z == 1) ? bk : bv;
    __bf16* Yb = (z == 0) ? Qp : (z == 1) ? Kp : Vt;
    int mode = (z == 2) ? 1 : 0;
    float oscale = (z == 0) ? 0.125f : 1.0f;   // fold 1/sqrt(D_K) into Q
    gemm_body_bf16(X, Wt, bias, nullptr, Yb, nullptr, mode, oscale,
                   blockIdx.y * 128, blockIdx.x * 128);
}

__global__ __launch_bounds__(256) void oproj_kernel(
    const __bf16* __restrict__ Cxb, const __bf16* __restrict__ WtO,
    const float* __restrict__ bo, const float* __restrict__ resid,
    float* __restrict__ pre)
{
    gemm_body_bf16(Cxb, WtO, bo, resid, nullptr, pre, 2, 1.0f,
                   blockIdx.y * 128, blockIdx.x * 128);
}

// ---------------- flash attention, key-split x2: 8 waves/block, 32 q-rows/wave,
// 32x32x16 MFMA, dbuf swizzled LDS K/V + async reg prefetch, in-reg softmax.
// Each block does 1024 of the 2048 keys; stores unnormalized O (bf16) + (m,l).
__global__ __launch_bounds__(512, 4) void attn_kernel(
    const __bf16* __restrict__ Qp, const __bf16* __restrict__ Kp,
    const __bf16* __restrict__ Vt, __bf16* __restrict__ Op, float2* __restrict__ ML)
{
    __shared__ __attribute__((aligned(16))) __bf16 Kl[2][4096];
    __shared__ __attribute__((aligned(16))) __bf16 Vl[2][4096];
    const int t = threadIdx.x;
    const int w = t >> 6, lane = t & 63;
    const int l31 = lane & 31, hi = lane >> 5;

    // XCD swizzle: 512 blocks, XCD x owns logical [64x,64x+64) -> 4 consecutive bh
    const int id = blockIdx.x;
    const int logical = (id & 7) * 64 + (id >> 3);
    const int bh = logical >> 4, rr = logical & 15;
    const int qs = rr >> 1, half = rr & 1;
    const int b = bh >> 4, h = bh & 15;
    const size_t tokQ = (size_t)b * SL + qs * 256 + w * 32;
    const size_t kbase = (size_t)b * SL + half * 1024;
    const size_t vrow0 = (size_t)bh * 64;

    const int srow = t >> 3, scol = (t & 7) << 3;
    const __bf16* gK = &Kp[(kbase + srow) * DM + h * 64 + scol];
    const __bf16* gV = &Vt[(vrow0 + srow) * SL + half * 1024 + scol];
    const int sidx = ((srow * 128 + scol * 2) ^ ((srow & 7) << 4)) >> 1;

    bf16x8 bq[4];
#pragma unroll
    for (int ks = 0; ks < 4; ++ks)
        bq[ks] = *reinterpret_cast<const bf16x8*>(
            &Qp[(tokQ + l31) * DM + h * 64 + ks * 16 + hi * 8]);

    f32x16 o0, o1;
#pragma unroll
    for (int r = 0; r < 16; ++r) { o0[r] = 0.f; o1[r] = 0.f; }
    float m_run = -1e30f, l_run = 0.f;

    const int swz = (l31 & 7) << 4;
    const int NT = 1024 / 64;   // 16 key tiles per block

    {
        bf16x8 kv = *reinterpret_cast<const bf16x8*>(gK);
        bf16x8 vv = *reinterpret_cast<const bf16x8*>(gV);
        *reinterpret_cast<bf16x8*>(&Kl[0][sidx]) = kv;
        *reinterpret_cast<bf16x8*>(&Vl[0][sidx]) = vv;
    }

    for (int ti = 0; ti < NT; ++ti) {
        const int cb = ti & 1;
        const bool pf = (ti + 1 < NT);
        bf16x8 kvn, vvn;
        if (pf) {   // async-STAGE: issue next-tile loads, consume after compute
            kvn = *reinterpret_cast<const bf16x8*>(gK + (size_t)(ti + 1) * 64 * DM);
            vvn = *reinterpret_cast<const bf16x8*>(gV + (ti + 1) * 64);
        }
        __syncthreads();

        // ---- QK^T (swapped): C[key][q], lane owns q-row l31
        f32x16 c0, c1;
#pragma unroll
        for (int r = 0; r < 16; ++r) { c0[r] = 0.f; c1[r] = 0.f; }
        __builtin_amdgcn_s_setprio(1);
#pragma unroll
        for (int ks = 0; ks < 4; ++ks) {
            int off = ks * 32 + hi * 16;
            bf16x8 ak0 = *reinterpret_cast<const bf16x8*>(&Kl[cb][((l31 * 128 + off) ^ swz) >> 1]);
            bf16x8 ak1 = *reinterpret_cast<const bf16x8*>(&Kl[cb][(((32 + l31) * 128 + off) ^ swz) >> 1]);
            c0 = mfma32(ak0, bq[ks], c0);
            c1 = mfma32(ak1, bq[ks], c1);
        }
        __builtin_amdgcn_s_setprio(0);

        float tm = c0[0];
#pragma unroll
        for (int r = 1; r < 16; ++r) tm = fmaxf(tm, c0[r]);
#pragma unroll
        for (int r = 0; r < 16; ++r) tm = fmaxf(tm, c1[r]);
        tm = fmaxf(tm, __shfl_xor(tm, 32));

        if (__any(tm > m_run + 8.f)) {   // defer-max
            float nm = fmaxf(m_run, tm);
            float sc = __expf(m_run - nm);
            m_run = nm;
            l_run *= sc;
#pragma unroll
            for (int r = 0; r < 16; ++r) {
                float sq = __shfl(sc, (r & 3) + 8 * (r >> 2) + 4 * hi);
                o0[r] *= sq; o1[r] *= sq;
            }
        }

        float rs = 0.f;
#pragma unroll
        for (int r = 0; r < 16; ++r) { c0[r] = __expf(c0[r] - m_run); rs += c0[r]; }
#pragma unroll
        for (int r = 0; r < 16; ++r) { c1[r] = __expf(c1[r] - m_run); rs += c1[r]; }
        rs += __shfl_xor(rs, 32);
        l_run += rs;

        unsigned wd0[8], wd1[8];
#pragma unroll
        for (int tt = 0; tt < 4; ++tt)
#pragma unroll
            for (int p = 0; p < 2; ++p) {
                wd0[tt * 2 + p] = packbf(c0[4 * tt + 2 * p], c0[4 * tt + 2 * p + 1]);
                wd1[tt * 2 + p] = packbf(c1[4 * tt + 2 * p], c1[4 * tt + 2 * p + 1]);
            }
        unsigned ua[4][4];
#pragma unroll
        for (int s = 0; s < 4; ++s) {
            int tA = (s & 1) * 2;
#pragma unroll
            for (int p = 0; p < 2; ++p) {
                unsigned A, B;
                if (s < 2) half_swap(wd0[tA * 2 + p], wd0[(tA + 1) * 2 + p], hi, A, B);
                else       half_swap(wd1[tA * 2 + p], wd1[(tA + 1) * 2 + p], hi, A, B);
                ua[s][p] = A; ua[s][2 + p] = B;
            }
        }

        __builtin_amdgcn_s_setprio(1);
#pragma unroll
        for (int s = 0; s < 4; ++s) {
            bf16x8 as = *reinterpret_cast<const bf16x8*>(&ua[s][0]);
            bf16x8 vf0 = *reinterpret_cast<const bf16x8*>(
                &Vl[cb][((l31 * 128 + s * 32 + hi * 16) ^ swz) >> 1]);
            bf16x8 vf1 = *reinterpret_cast<const bf16x8*>(
                &Vl[cb][(((32 + l31) * 128 + s * 32 + hi * 16) ^ swz) >> 1]);
            o0 = mfma32(as, vf0, o0);
            o1 = mfma32(as, vf1, o1);
        }
        __builtin_amdgcn_s_setprio(0);

        if (pf) {
            *reinterpret_cast<bf16x8*>(&Kl[cb ^ 1][sidx]) = kvn;
            *reinterpret_cast<bf16x8*>(&Vl[cb ^ 1][sidx]) = vvn;
        }
    }

    // ---- store unnormalized partial + (m,l)
    if (hi == 0)
        ML[((size_t)half * 4096 + tokQ + l31) * NHEAD + h] = float2{m_run, l_run};
    const size_t obase = (size_t)half * 4096 * DM;
#pragma unroll
    for (int r = 0; r < 16; ++r) {
        int qq = (r & 3) + 8 * (r >> 2) + 4 * hi;
        size_t rowi = obase + (tokQ + qq) * DM + h * 64;
        Op[rowi + l31]      = (__bf16)o0[r];
        Op[rowi + 32 + l31] = (__bf16)o1[r];
    }
}

// ---------------- combine the two key-half partials -> normalized ctx (bf16)
__global__ __launch_bounds__(256) void combine_kernel(
    const __bf16* __restrict__ Op, const float2* __restrict__ ML,
    __bf16* __restrict__ Cxb)
{
    const size_t e = ((size_t)blockIdx.x * 256 + threadIdx.x) * 8;
    const int token = (int)(e >> 10);
    const int h = (int)((e >> 6) & 15);
    float2 ml0 = ML[(size_t)token * NHEAD + h];
    float2 ml1 = ML[((size_t)4096 + token) * NHEAD + h];
    float M = fmaxf(ml0.x, ml1.x);
    float s0 = __expf(ml0.x - M), s1 = __expf(ml1.x - M);
    float inv = 1.f / (ml0.y * s0 + ml1.y * s1);
    s0 *= inv; s1 *= inv;
    bf16x8 a0 = *reinterpret_cast<const bf16x8*>(&Op[e]);
    bf16x8 a1 = *reinterpret_cast<const bf16x8*>(&Op[(size_t)4096 * DM + e]);
    bf16x8 o;
#pragma unroll
    for (int j = 0; j < 8; ++j)
        o[j] = (__bf16)((float)a0[j] * s0 + (float)a1[j] * s1);
    *reinterpret_cast<bf16x8*>(&Cxb[e]) = o;
}

// ---------------- LayerNorm over rows of 1024
__global__ __launch_bounds__(256) void ln_kernel(
    const float* __restrict__ X, const float* __restrict__ gamma,
    const float* __restrict__ beta, float* __restrict__ out)
{
    const int row = blockIdx.x, t = threadIdx.x;
    float4 v = *reinterpret_cast<const float4*>(&X[(size_t)row * DM + t * 4]);
    float s = v.x + v.y + v.z + v.w;
    float s2 = v.x * v.x + v.y * v.y + v.z * v.z + v.w * v.w;
#pragma unroll
    for (int off = 1; off < 64; off <<= 1) {
        s += __shfl_xor(s, off);
        s2 += __shfl_xor(s2, off);
    }
    __shared__ float rs[4], rs2[4];
    const int w = t >> 6;
    if ((t & 63) == 0) { rs[w] = s; rs2[w] = s2; }
    __syncthreads();
    s = rs[0] + rs[1] + rs[2] + rs[3];
    s2 = rs2[0] + rs2[1] + rs2[2] + rs2[3];
    float mean = s * (1.f / DM);
    float var = s2 * (1.f / DM) - mean * mean;
    float rstd = rsqrtf(var + 1e-5f);
    int c = t * 4;
    float4 o;
    o.x = (v.x - mean) * rstd * gamma[c + 0] + beta[c + 0];
    o.y = (v.y - mean) * rstd * gamma[c + 1] + beta[c + 1];
    o.z = (v.z - mean) * rstd * gamma[c + 2] + beta[c + 2];
    o.w = (v.w - mean) * rstd * gamma[c + 3] + beta[c + 3];
    *reinterpret_cast<float4*>(&out[(size_t)row * DM + c]) = o;
}

extern "C" void kernel_launch(void* const* d_in, const int* in_sizes, int n_in,
                              void* d_out, int out_size, void* d_ws, size_t ws_size,
                              hipStream_t stream) {
    (void)in_sizes; (void)n_in; (void)out_size; (void)ws_size;
    const float* q   = (const float*)d_in[0];
    const float* k   = (const float*)d_in[1];
    const float* v   = (const float*)d_in[2];
    const float* Wq  = (const float*)d_in[3];
    const float* bq  = (const float*)d_in[4];
    const float* Wk  = (const float*)d_in[5];
    const float* bk  = (const float*)d_in[6];
    const float* Wv  = (const float*)d_in[7];
    const float* bv  = (const float*)d_in[8];
    const float* Wo  = (const float*)d_in[9];
    const float* bo  = (const float*)d_in[10];
    const float* lng = (const float*)d_in[11];
    const float* lnb = (const float*)d_in[12];

    char* ws = (char*)d_ws;
    const size_t MB = (size_t)1 << 20;
    __bf16* WtQ = (__bf16*)(ws + 0 * MB);
    __bf16* WtK = (__bf16*)(ws + 2 * MB);
    __bf16* WtV = (__bf16*)(ws + 4 * MB);
    __bf16* WtO = (__bf16*)(ws + 6 * MB);
    __bf16* Xbq = (__bf16*)(ws + 8 * MB);    // [4096][1024] bf16 (dead after qkv)
    __bf16* Xbk = (__bf16*)(ws + 16 * MB);   // (dead after qkv)
    __bf16* Xbv = (__bf16*)(ws + 24 * MB);   // (dead after qkv)
    __bf16* Qp  = (__bf16*)(ws + 32 * MB);   // pre-scaled by 1/8
    __bf16* Kp  = (__bf16*)(ws + 40 * MB);
    __bf16* Vt  = (__bf16*)(ws + 48 * MB);   // [b][h][64][2048]
    __bf16* Cxb = (__bf16*)(ws + 56 * MB);   // ctx bf16 [4096][1024]
    // overlays (all ordering enforced by stream):
    __bf16* Op  = (__bf16*)(ws + 8 * MB);    // attn partials [2][4096][1024] bf16 (16 MB)
    float2* ML  = (float2*)(ws + 24 * MB);   // [2][4096][16] float2 (1 MB)
    float*  pre = (float*)(ws + 8 * MB);     // oproj out f32 (16 MB; Op dead by then)

    cast_kernel<<<dim3(2048, 3), 256, 0, stream>>>(q, k, v, Xbq, Xbk, Xbv);
    wt4_kernel<<<dim3(32, 32, 4), dim3(32, 8), 0, stream>>>(
        Wq, Wk, Wv, Wo, WtQ, WtK, WtV, WtO);

    qkv_kernel<<<dim3(8, 32, 3), 256, 0, stream>>>(Xbq, Xbk, Xbv, WtQ, WtK, WtV,
                                                   bq, bk, bv, Qp, Kp, Vt);
    attn_kernel<<<dim3(512), 512, 0, stream>>>(Qp, Kp, Vt, Op, ML);
    combine_kernel<<<dim3(2048), 256, 0, stream>>>(Op, ML, Cxb);
    oproj_kernel<<<dim3(8, 32), 256, 0, stream>>>(Cxb, WtO, bo, q, pre);
    ln_kernel<<<4096, 256, 0, stream>>>(pre, lng, lnb, (float*)d_out);
}